// Round 1
// baseline (42429.907 us; speedup 1.0000x reference)
//
#include <hip/hip_runtime.h>
#include <math.h>

// Problem constants (fixed by the reference).
#define BQ   16384
#define FQ   64
#define NBQ  64
#define HD   128     // H1 == H2 == 128
#define TB   32      // batch rows per block
#define NT   512     // threads per block (8 waves)

// LDS row strides (floats), padded to stay 16B-aligned and break bank patterns.
#define RBF_LD 68
#define HS_LD  132

__device__ __forceinline__ float gelu_exact(float v) {
    return 0.5f * v * (1.0f + erff(v * 0.70710678118654752f));
}

__device__ __forceinline__ float softplus_stable(float v) {
    return (v > 0.0f) ? (v + log1pf(expf(-v))) : log1pf(expf(v));
}

// ---------------- att softmax (64 elems, 1 wave) ----------------
__global__ void __launch_bounds__(64) nam_att_softmax(const float* __restrict__ att,
                                                      float* __restrict__ w) {
    const int l = threadIdx.x;
    float v = att[l];
    float m = v;
#pragma unroll
    for (int s = 32; s >= 1; s >>= 1) m = fmaxf(m, __shfl_xor(m, s, 64));
    float e = expf(v - m);
    float ssum = e;
#pragma unroll
    for (int s = 32; s >= 1; s >>= 1) ssum += __shfl_xor(ssum, s, 64);
    w[l] = e / ssum;
}

// ---------------- fused per-feature NAM body ----------------
// grid = BQ/TB = 512 blocks, 512 threads. Each block owns 32 batch rows and
// loops over all 64 features, accumulating agg in registers.
__global__ void __launch_bounds__(NT) nam_main(
    const float* __restrict__ x,
    const float* __restrict__ centers,
    const float* __restrict__ log_widths,
    const float* __restrict__ W1,
    const float* __restrict__ b1,
    const float* __restrict__ g1,
    const float* __restrict__ be1,
    const float* __restrict__ W2,
    const float* __restrict__ b2,
    const float* __restrict__ g2,
    const float* __restrict__ be2,
    const float* __restrict__ Wr,
    const float* __restrict__ br,
    const float* __restrict__ bias,
    const float* __restrict__ wsoft,
    float* __restrict__ agg_out)
{
    __shared__ float wbuf[NBQ * HD];        // 32 KB weight staging buffer
    __shared__ float hbuf[TB * HS_LD];      // aliased: rbf tile [TB][68] / h tile [TB][132]
    __shared__ float part_s[16][TB];
    __shared__ float part_q[16][TB];
    __shared__ float mus[TB];
    __shared__ float rsigs[TB];

    const int t  = threadIdx.x;
    const int c  = t & 127;       // hidden column 0..127
    const int g  = t >> 7;        // row group 0..3
    const int r0 = g * 8;         // first of this thread's 8 rows
    const int b0 = blockIdx.x * TB;

    float4* wb4 = (float4*)wbuf;

    float acc[8];
#pragma unroll
    for (int r = 0; r < 8; ++r) acc[r] = 0.0f;

    for (int f = 0; f < FQ; ++f) {
        __syncthreads();  // previous iteration's LDS readers are done

        // ---- stage W1[f] into LDS; compute rbf tile into hbuf (stride 68) ----
        {
            const float4* W1f = (const float4*)(W1 + (size_t)f * NBQ * HD);
#pragma unroll
            for (int i = 0; i < 4; ++i) wb4[t + i * NT] = W1f[t + i * NT];
        }
        const float wf   = wsoft[f];
        const float wf01 = 0.1f * wf;
        const float b1v  = b1[f * HD + c];
        const float g1v  = g1[f * HD + c];
        const float be1v = be1[f * HD + c];

        {
            const int row = t >> 4;     // 0..31
            const int sub = t & 15;     // 4 centers each
            float xv = x[(b0 + row) * FQ + f];
            xv = fminf(fmaxf(xv, -10.0f), 10.0f);
#pragma unroll
            for (int i = 0; i < 4; ++i) {
                const int n = sub * 4 + i;
                const float cen = centers[f * NBQ + n];
                float lw = log_widths[f * NBQ + n];
                lw = fminf(fmaxf(lw, -5.0f), 5.0f);
                const float wid = expf(lw) + 0.1f;
                float d = (xv - cen) / wid;
                d = fminf(fmaxf(d, -10.0f), 10.0f);
                hbuf[row * RBF_LD + n] = expf(-0.5f * d * d);
            }
        }
        __syncthreads();

        // ---- h1 = rbf @ W1 + b1 (rbf reads are wave-broadcast; W1 reads stride-1) ----
        float h1[8];
#pragma unroll
        for (int r = 0; r < 8; ++r) h1[r] = b1v;
        for (int n = 0; n < NBQ; n += 4) {
            const float w0 = wbuf[(n + 0) * HD + c];
            const float w1_ = wbuf[(n + 1) * HD + c];
            const float w2_ = wbuf[(n + 2) * HD + c];
            const float w3_ = wbuf[(n + 3) * HD + c];
#pragma unroll
            for (int r = 0; r < 8; ++r) {
                const float4 rv = *(const float4*)&hbuf[(r0 + r) * RBF_LD + n];
                h1[r] = fmaf(rv.x, w0, h1[r]);
                h1[r] = fmaf(rv.y, w1_, h1[r]);
                h1[r] = fmaf(rv.z, w2_, h1[r]);
                h1[r] = fmaf(rv.w, w3_, h1[r]);
            }
        }
        __syncthreads();  // GEMM1 done -> wbuf reusable

        // ---- stage Wr[f]; res = rbf @ Wr + br, folded into acc ----
        {
            const float4* Wrf = (const float4*)(Wr + (size_t)f * NBQ * HD);
#pragma unroll
            for (int i = 0; i < 4; ++i) wb4[t + i * NT] = Wrf[t + i * NT];
        }
        const float brv = br[f * HD + c];
        __syncthreads();

        {
            float resv[8];
#pragma unroll
            for (int r = 0; r < 8; ++r) resv[r] = brv;
            for (int n = 0; n < NBQ; n += 4) {
                const float w0 = wbuf[(n + 0) * HD + c];
                const float w1_ = wbuf[(n + 1) * HD + c];
                const float w2_ = wbuf[(n + 2) * HD + c];
                const float w3_ = wbuf[(n + 3) * HD + c];
#pragma unroll
                for (int r = 0; r < 8; ++r) {
                    const float4 rv = *(const float4*)&hbuf[(r0 + r) * RBF_LD + n];
                    resv[r] = fmaf(rv.x, w0, resv[r]);
                    resv[r] = fmaf(rv.y, w1_, resv[r]);
                    resv[r] = fmaf(rv.z, w2_, resv[r]);
                    resv[r] = fmaf(rv.w, w3_, resv[r]);
                }
            }
#pragma unroll
            for (int r = 0; r < 8; ++r) acc[r] = fmaf(wf01, resv[r], acc[r]);
        }
        __syncthreads();  // res done: rbf region dead, wbuf reusable

        // ---- write raw h1 tile (stride 132); stage W2 half 1 ----
#pragma unroll
        for (int r = 0; r < 8; ++r) hbuf[(r0 + r) * HS_LD + c] = h1[r];
        {
            const float4* W2f = (const float4*)(W2 + (size_t)f * HD * HD);
#pragma unroll
            for (int i = 0; i < 4; ++i) wb4[t + i * NT] = W2f[t + i * NT];
        }
        const float b2v  = b2[f * HD + c];
        const float g2v  = g2[f * HD + c];
        const float be2v = be2[f * HD + c];
        __syncthreads();

        // ---- LN1 stats: 16 threads per row ----
        {
            const int row = t & 31;
            const int sub = t >> 5;     // 0..15, 8 cols each
            const float4 v0 = *(const float4*)&hbuf[row * HS_LD + sub * 8];
            const float4 v1 = *(const float4*)&hbuf[row * HS_LD + sub * 8 + 4];
            const float s = v0.x + v0.y + v0.z + v0.w + v1.x + v1.y + v1.z + v1.w;
            const float q = v0.x*v0.x + v0.y*v0.y + v0.z*v0.z + v0.w*v0.w
                          + v1.x*v1.x + v1.y*v1.y + v1.z*v1.z + v1.w*v1.w;
            part_s[sub][row] = s;
            part_q[sub][row] = q;
        }
        __syncthreads();
        if (t < TB) {
            float s = 0.0f, q = 0.0f;
#pragma unroll
            for (int i = 0; i < 16; ++i) { s += part_s[i][t]; q += part_q[i][t]; }
            const float mu  = s * (1.0f / 128.0f);
            const float var = q * (1.0f / 128.0f) - mu * mu;
            mus[t]   = mu;
            rsigs[t] = rsqrtf(var + 1e-5f);
        }
        __syncthreads();

        // ---- apply LN1 + gelu, write h1g in place ----
#pragma unroll
        for (int r = 0; r < 8; ++r) {
            const int row = r0 + r;
            const float v = (h1[r] - mus[row]) * rsigs[row] * g1v + be1v;
            hbuf[row * HS_LD + c] = gelu_exact(v);
        }
        __syncthreads();  // h1g + W2 half1 ready

        // ---- h2 = h1g @ W2 + b2 (two 32KB halves of W2) ----
        float h2[8];
#pragma unroll
        for (int r = 0; r < 8; ++r) h2[r] = b2v;
        for (int j = 0; j < 64; j += 4) {
            const float w0 = wbuf[(j + 0) * HD + c];
            const float w1_ = wbuf[(j + 1) * HD + c];
            const float w2_ = wbuf[(j + 2) * HD + c];
            const float w3_ = wbuf[(j + 3) * HD + c];
#pragma unroll
            for (int r = 0; r < 8; ++r) {
                const float4 hv = *(const float4*)&hbuf[(r0 + r) * HS_LD + j];
                h2[r] = fmaf(hv.x, w0, h2[r]);
                h2[r] = fmaf(hv.y, w1_, h2[r]);
                h2[r] = fmaf(hv.z, w2_, h2[r]);
                h2[r] = fmaf(hv.w, w3_, h2[r]);
            }
        }
        __syncthreads();  // half1 consumed
        {
            const float4* W2f = (const float4*)(W2 + (size_t)f * HD * HD);
#pragma unroll
            for (int i = 0; i < 4; ++i) wb4[t + i * NT] = W2f[2048 + t + i * NT];
        }
        __syncthreads();
        for (int j = 64; j < 128; j += 4) {
            const float w0 = wbuf[(j - 64 + 0) * HD + c];
            const float w1_ = wbuf[(j - 64 + 1) * HD + c];
            const float w2_ = wbuf[(j - 64 + 2) * HD + c];
            const float w3_ = wbuf[(j - 64 + 3) * HD + c];
#pragma unroll
            for (int r = 0; r < 8; ++r) {
                const float4 hv = *(const float4*)&hbuf[(r0 + r) * HS_LD + j];
                h2[r] = fmaf(hv.x, w0, h2[r]);
                h2[r] = fmaf(hv.y, w1_, h2[r]);
                h2[r] = fmaf(hv.z, w2_, h2[r]);
                h2[r] = fmaf(hv.w, w3_, h2[r]);
            }
        }
        __syncthreads();  // GEMM2 done: hbuf reusable

        // ---- LN2 stats on raw h2 ----
#pragma unroll
        for (int r = 0; r < 8; ++r) hbuf[(r0 + r) * HS_LD + c] = h2[r];
        __syncthreads();
        {
            const int row = t & 31;
            const int sub = t >> 5;
            const float4 v0 = *(const float4*)&hbuf[row * HS_LD + sub * 8];
            const float4 v1 = *(const float4*)&hbuf[row * HS_LD + sub * 8 + 4];
            const float s = v0.x + v0.y + v0.z + v0.w + v1.x + v1.y + v1.z + v1.w;
            const float q = v0.x*v0.x + v0.y*v0.y + v0.z*v0.z + v0.w*v0.w
                          + v1.x*v1.x + v1.y*v1.y + v1.z*v1.z + v1.w*v1.w;
            part_s[sub][row] = s;
            part_q[sub][row] = q;
        }
        __syncthreads();
        if (t < TB) {
            float s = 0.0f, q = 0.0f;
#pragma unroll
            for (int i = 0; i < 16; ++i) { s += part_s[i][t]; q += part_q[i][t]; }
            const float mu  = s * (1.0f / 128.0f);
            const float var = q * (1.0f / 128.0f) - mu * mu;
            mus[t]   = mu;
            rsigs[t] = rsqrtf(var + 1e-5f);
        }
        __syncthreads();

        // ---- apply LN2 + gelu, accumulate attention-weighted aggregate ----
#pragma unroll
        for (int r = 0; r < 8; ++r) {
            const int row = r0 + r;
            const float v = (h2[r] - mus[row]) * rsigs[row] * g2v + be2v;
            acc[r] = fmaf(wf, gelu_exact(v), acc[r]);
        }
    }

    // ---- epilogue: agg = acc + bias, coalesced store to workspace ----
    const float biasv = bias[c];
#pragma unroll
    for (int r = 0; r < 8; ++r) {
        agg_out[(size_t)(b0 + r0 + r) * HD + c] = acc[r] + biasv;
    }
}

// ---------------- mixture-beta head: one wave per batch row ----------------
__global__ void __launch_bounds__(256) nam_head(
    const float* __restrict__ agg,
    const float* __restrict__ Wpi, const float* __restrict__ bpi,
    const float* __restrict__ Wa,  const float* __restrict__ ba,
    const float* __restrict__ Wb,  const float* __restrict__ bb,
    float* __restrict__ out)
{
    const int gid  = blockIdx.x * blockDim.x + threadIdx.x;
    const int row  = gid >> 6;
    const int lane = threadIdx.x & 63;
    if (row >= BQ) return;

    const float2 a = ((const float2*)(agg + (size_t)row * HD))[lane];

    const float2* wp = (const float2*)Wpi;
    const float2* wa = (const float2*)Wa;
    const float2* wb = (const float2*)Wb;
    const float2 p01 = wp[lane * 3], p23 = wp[lane * 3 + 1], p45 = wp[lane * 3 + 2];
    const float2 a01 = wa[lane * 3], a23 = wa[lane * 3 + 1], a45 = wa[lane * 3 + 2];
    const float2 b01 = wb[lane * 3], b23 = wb[lane * 3 + 1], b45 = wb[lane * 3 + 2];

    // partials: rows h=2*lane (k0,k1,k2) and h=2*lane+1 (k0,k1,k2)
    float ppi0 = a.x * p01.x + a.y * p23.y;
    float ppi1 = a.x * p01.y + a.y * p45.x;
    float ppi2 = a.x * p23.x + a.y * p45.y;
    float pa0  = a.x * a01.x + a.y * a23.y;
    float pa1  = a.x * a01.y + a.y * a45.x;
    float pa2  = a.x * a23.x + a.y * a45.y;
    float pb0  = a.x * b01.x + a.y * b23.y;
    float pb1  = a.x * b01.y + a.y * b45.x;
    float pb2  = a.x * b23.x + a.y * b45.y;

#pragma unroll
    for (int s = 32; s >= 1; s >>= 1) {
        ppi0 += __shfl_xor(ppi0, s, 64);
        ppi1 += __shfl_xor(ppi1, s, 64);
        ppi2 += __shfl_xor(ppi2, s, 64);
        pa0  += __shfl_xor(pa0,  s, 64);
        pa1  += __shfl_xor(pa1,  s, 64);
        pa2  += __shfl_xor(pa2,  s, 64);
        pb0  += __shfl_xor(pb0,  s, 64);
        pb1  += __shfl_xor(pb1,  s, 64);
        pb2  += __shfl_xor(pb2,  s, 64);
    }

    if (lane == 0) {
        const float z0 = ppi0 + bpi[0], z1 = ppi1 + bpi[1], z2 = ppi2 + bpi[2];
        const float mz = fmaxf(z0, fmaxf(z1, z2));
        const float e0 = expf(z0 - mz), e1 = expf(z1 - mz), e2 = expf(z2 - mz);
        const float es = e0 + e1 + e2;

        const float al0 = fminf(fmaxf(softplus_stable(pa0 + ba[0]) + 1.01f, 1.01f), 100.0f);
        const float al1 = fminf(fmaxf(softplus_stable(pa1 + ba[1]) + 1.01f, 1.01f), 100.0f);
        const float al2 = fminf(fmaxf(softplus_stable(pa2 + ba[2]) + 1.01f, 1.01f), 100.0f);
        const float bt0 = fminf(fmaxf(softplus_stable(pb0 + bb[0]) + 1.01f, 1.01f), 100.0f);
        const float bt1 = fminf(fmaxf(softplus_stable(pb1 + bb[1]) + 1.01f, 1.01f), 100.0f);
        const float bt2 = fminf(fmaxf(softplus_stable(pb2 + bb[2]) + 1.01f, 1.01f), 100.0f);

        const float pred = (e0 * (al0 / (al0 + bt0))
                          + e1 * (al1 / (al1 + bt1))
                          + e2 * (al2 / (al2 + bt2))) / es;
        out[row] = fminf(fmaxf(pred, 0.001f), 0.999f);
    }
}

extern "C" void kernel_launch(void* const* d_in, const int* in_sizes, int n_in,
                              void* d_out, int out_size, void* d_ws, size_t ws_size,
                              hipStream_t stream) {
    const float* x          = (const float*)d_in[0];
    const float* centers    = (const float*)d_in[1];
    const float* log_widths = (const float*)d_in[2];
    const float* W1   = (const float*)d_in[3];
    const float* b1   = (const float*)d_in[4];
    const float* g1   = (const float*)d_in[5];
    const float* be1  = (const float*)d_in[6];
    const float* W2   = (const float*)d_in[7];
    const float* b2   = (const float*)d_in[8];
    const float* g2   = (const float*)d_in[9];
    const float* be2  = (const float*)d_in[10];
    const float* Wr   = (const float*)d_in[11];
    const float* br   = (const float*)d_in[12];
    const float* att  = (const float*)d_in[13];
    const float* bias = (const float*)d_in[14];
    const float* Wpi  = (const float*)d_in[15];
    const float* bpi  = (const float*)d_in[16];
    const float* Wa   = (const float*)d_in[17];
    const float* ba   = (const float*)d_in[18];
    const float* Wb   = (const float*)d_in[19];
    const float* bb   = (const float*)d_in[20];

    float* wsp   = (float*)d_ws;
    float* wsoft = wsp;          // 64 floats
    float* agg   = wsp + 64;     // BQ*HD floats (8 MB)

    nam_att_softmax<<<1, 64, 0, stream>>>(att, wsoft);
    nam_main<<<BQ / TB, NT, 0, stream>>>(x, centers, log_widths, W1, b1, g1, be1,
                                         W2, b2, g2, be2, Wr, br, bias, wsoft, agg);
    nam_head<<<(BQ / 4), 256, 0, stream>>>(agg, Wpi, bpi, Wa, ba, Wb, bb, (float*)d_out);
}

// Round 2
// 475.349 us; speedup vs baseline: 89.2605x; 89.2605x over previous
//
#include <hip/hip_runtime.h>
#include <math.h>

// Problem constants (fixed by the reference).
#define BQ   16384
#define FQ   64
#define NBQ  64
#define HD   128
#define KQ   3

typedef __attribute__((ext_vector_type(8))) short s16x8;   // 8 bf16 (4 VGPRs)
typedef __attribute__((ext_vector_type(4))) float f32x4;   // MFMA C/D

// round-to-nearest-even fp32 -> bf16
__device__ __forceinline__ unsigned short f2bf(float x) {
    unsigned int u = __float_as_uint(x);
    unsigned int r = (u + 0x7FFFu + ((u >> 16) & 1u)) >> 16;
    return (unsigned short)r;
}

// gelu(v) = 0.5 v (1 + tanh(0.79788456(v + 0.044715 v^3)))
//         = v * sigmoid(1.5957691 v + 0.07135481 v^3)   (exact tanh identity)
__device__ __forceinline__ float gelu_fast(float v) {
    const float v2 = v * v;
    const float s  = fmaf(0.07135481f * v2, v, 1.5957691f * v);
    const float e  = __expf(-s);
    return v * (1.0f / (1.0f + e));
}

__device__ __forceinline__ float softplus_stable(float v) {
    return (v > 0.0f) ? (v + log1pf(expf(-v))) : log1pf(expf(v));
}

// async 16B global->LDS (wave-uniform LDS base + lane*16; gptr per-lane)
__device__ __forceinline__ void load16_lds(const unsigned short* g, unsigned short* l) {
    __builtin_amdgcn_global_load_lds(
        (const __attribute__((address_space(1))) unsigned int*)(uintptr_t)g,
        (__attribute__((address_space(3))) unsigned int*)(uintptr_t)l,   // AS3 is 32-bit: low bits = LDS offset
        16, 0, 0);
}

// ---------------- att softmax (64 elems, 1 wave) ----------------
__global__ void __launch_bounds__(64) nam_att_softmax(const float* __restrict__ att,
                                                      float* __restrict__ w) {
    const int l = threadIdx.x;
    float v = att[l];
    float m = v;
#pragma unroll
    for (int s = 32; s >= 1; s >>= 1) m = fmaxf(m, __shfl_xor(m, s, 64));
    float e = expf(v - m);
    float ssum = e;
#pragma unroll
    for (int s = 32; s >= 1; s >>= 1) ssum += __shfl_xor(ssum, s, 64);
    w[l] = e / ssum;
}

// ---------------- prep: reciprocal widths ----------------
__global__ void __launch_bounds__(256) nam_rwid(const float* __restrict__ lw,
                                                float* __restrict__ rwid) {
    const int id = blockIdx.x * 256 + threadIdx.x;
    if (id >= FQ * NBQ) return;
    float l = fminf(fmaxf(lw[id], -5.0f), 5.0f);
    rwid[id] = 1.0f / (expf(l) + 0.1f);
}

// ---------------- prep: x transpose ----------------
__global__ void __launch_bounds__(256) nam_xtr(const float* __restrict__ x,
                                               float* __restrict__ xT) {
    const int id = blockIdx.x * 256 + threadIdx.x;   // 1,048,576
    const int row = id & (BQ - 1);
    const int f   = id >> 14;
    xT[id] = x[(size_t)row * FQ + f];
}

// ---------------- prep: weight convert + swizzle into MFMA B-frag order ----
// dst elem off = f*K*128 + ((nt*(K/8) + kb)*16 + n)*8 + j  <->  W[f][kb*8+j][nt*16+n]
// Lane l=16q+n of k-chunk c then reads 16B at (nt*(K/8)+c*4)*256 + l*16: fully linear.
__global__ void __launch_bounds__(256) nam_swz(const float* __restrict__ W,
                                               unsigned short* __restrict__ dst,
                                               const int K) {
    const int id = blockIdx.x * 256 + threadIdx.x;
    const int KB = K >> 3;
    if (id >= FQ * 8 * KB * 16) return;
    const int nn = id & 15;
    const int kb = (id >> 4) % KB;
    const int nt = ((id >> 4) / KB) & 7;
    const int f  = id / (KB * 16 * 8);
    const float* src = W + ((size_t)f * K + kb * 8) * HD + nt * 16 + nn;
    s16x8 o;
#pragma unroll
    for (int j = 0; j < 8; ++j) o[j] = (short)f2bf(src[(size_t)j * HD]);
    *(s16x8*)(dst + (size_t)f * K * HD + ((size_t)(nt * KB + kb) * 16 + nn) * 8) = o;
}

// ---------------- fused MFMA NAM body ----------------
// grid 512 = 2 fgroups x 256 row-tiles(M=64). 256 threads (4 waves, 16 rows each).
__global__ void __launch_bounds__(256, 2) nam_main(
    const float* __restrict__ centers,
    const float* __restrict__ rwid,
    const float* __restrict__ xT,
    const unsigned short* __restrict__ W1s,
    const unsigned short* __restrict__ Wrs,
    const unsigned short* __restrict__ W2s,
    const float* __restrict__ b1, const float* __restrict__ g1, const float* __restrict__ be1,
    const float* __restrict__ b2, const float* __restrict__ g2, const float* __restrict__ be2,
    const float* __restrict__ br,
    const float* __restrict__ wsoft,
    float* __restrict__ aggP)
{
    __shared__ unsigned short wbuf[16384];     // 32KB: W1[0:8192]+Wr[8192:] then W2
    __shared__ unsigned short abuf[64 * 72];   // rbf tile, bf16, stride 72
    __shared__ unsigned short hbuf[64 * 136];  // h1g tile, bf16, stride 136

    const int t    = threadIdx.x;
    const int ln   = t & 63;
    const int wv   = t >> 6;        // wave 0..3
    const int n    = ln & 15;       // MFMA col / A-row m
    const int q    = ln >> 4;       // quad
    const int wrow = wv * 16;       // wave's row base in tile
    const int fg   = blockIdx.x & 1;
    const int rb   = blockIdx.x >> 1;
    const int b0   = rb * 64;

    f32x4 agg[8];
#pragma unroll
    for (int nt = 0; nt < 8; ++nt) agg[nt] = f32x4{0.f, 0.f, 0.f, 0.f};

    for (int ff = 0; ff < 32; ++ff) {
        const int f = fg * 32 + ((ff + rb) & 31);   // decorrelated feature order
        __syncthreads();   // barrier0: prev iter's wbuf(W2)/abuf readers done

        // ---- stage W1[f] + Wr[f] (32KB) async into LDS ----
        {
            const unsigned short* gw1 = W1s + (size_t)f * 8192;
            const unsigned short* gwr = Wrs + (size_t)f * 8192;
#pragma unroll
            for (int i = 0; i < 8; ++i) {
                const int chunk = i * 4 + wv;  // 32 x 1KB chunks
                const unsigned short* src = (chunk < 16) ? (gw1 + chunk * 512)
                                                         : (gwr + (chunk - 16) * 512);
                load16_lds(src + ln * 8, wbuf + chunk * 512);
            }
        }

        // ---- rbf tile -> abuf (bf16, stride 72) ----
        {
            const int row = t & 63;
            const int ng  = t >> 6;
            float xv = xT[(size_t)f * BQ + b0 + row];
            xv = fminf(fmaxf(xv, -10.0f), 10.0f);
            const float4* cen4 = (const float4*)(centers + f * NBQ + ng * 16);
            const float4* rw4  = (const float4*)(rwid    + f * NBQ + ng * 16);
            s16x8 v0, v1;
#pragma unroll
            for (int i2 = 0; i2 < 4; ++i2) {
                const float4 cc = cen4[i2];
                const float4 rr = rw4[i2];
                float d0 = fminf(fmaxf((xv - cc.x) * rr.x, -10.f), 10.f);
                float d1 = fminf(fmaxf((xv - cc.y) * rr.y, -10.f), 10.f);
                float d2 = fminf(fmaxf((xv - cc.z) * rr.z, -10.f), 10.f);
                float d3 = fminf(fmaxf((xv - cc.w) * rr.w, -10.f), 10.f);
                const short e0 = (short)f2bf(__expf(-0.5f * d0 * d0));
                const short e1 = (short)f2bf(__expf(-0.5f * d1 * d1));
                const short e2 = (short)f2bf(__expf(-0.5f * d2 * d2));
                const short e3 = (short)f2bf(__expf(-0.5f * d3 * d3));
                if (i2 < 2) { v0[i2*4+0]=e0; v0[i2*4+1]=e1; v0[i2*4+2]=e2; v0[i2*4+3]=e3; }
                else { v1[(i2-2)*4+0]=e0; v1[(i2-2)*4+1]=e1; v1[(i2-2)*4+2]=e2; v1[(i2-2)*4+3]=e3; }
            }
            *(s16x8*)&abuf[row * 72 + ng * 16]     = v0;
            *(s16x8*)&abuf[row * 72 + ng * 16 + 8] = v1;
        }
        __syncthreads();   // barrier1 (compiler drains vmcnt for the LDS-DMA)

        // ---- GEMM1 (h1) + GEMMr (res): A = rbf frags, K=64 ----
        const s16x8 a0 = *(const s16x8*)&abuf[(wrow + n) * 72 + q * 8];
        const s16x8 a1 = *(const s16x8*)&abuf[(wrow + n) * 72 + 32 + q * 8];
        f32x4 hc[8], rc[8];
#pragma unroll
        for (int nt = 0; nt < 8; ++nt) {
            const s16x8 bA = *(const s16x8*)&wbuf[(nt * 8 + 0) * 128 + ln * 8];
            const s16x8 bB = *(const s16x8*)&wbuf[(nt * 8 + 4) * 128 + ln * 8];
            f32x4 z = f32x4{0.f, 0.f, 0.f, 0.f};
            z = __builtin_amdgcn_mfma_f32_16x16x32_bf16(a0, bA, z, 0, 0, 0);
            z = __builtin_amdgcn_mfma_f32_16x16x32_bf16(a1, bB, z, 0, 0, 0);
            hc[nt] = z;
            const s16x8 cA = *(const s16x8*)&wbuf[8192 + (nt * 8 + 0) * 128 + ln * 8];
            const s16x8 cB = *(const s16x8*)&wbuf[8192 + (nt * 8 + 4) * 128 + ln * 8];
            f32x4 y = f32x4{0.f, 0.f, 0.f, 0.f};
            y = __builtin_amdgcn_mfma_f32_16x16x32_bf16(a0, cA, y, 0, 0, 0);
            y = __builtin_amdgcn_mfma_f32_16x16x32_bf16(a1, cB, y, 0, 0, 0);
            rc[nt] = y;
        }

        // ---- LN1 (+bias b1) fully in registers: rows q*4+i live in this quad ----
        float sm[4] = {0.f, 0.f, 0.f, 0.f}, sq[4] = {0.f, 0.f, 0.f, 0.f};
#pragma unroll
        for (int nt = 0; nt < 8; ++nt) {
            const float bv = b1[f * HD + nt * 16 + n];
#pragma unroll
            for (int i = 0; i < 4; ++i) {
                const float v = hc[nt][i] + bv;
                hc[nt][i] = v; sm[i] += v; sq[i] += v * v;
            }
        }
#pragma unroll
        for (int s = 1; s <= 8; s <<= 1) {
#pragma unroll
            for (int i = 0; i < 4; ++i) {
                sm[i] += __shfl_xor(sm[i], s, 64);
                sq[i] += __shfl_xor(sq[i], s, 64);
            }
        }
        float mu[4], rs[4];
#pragma unroll
        for (int i = 0; i < 4; ++i) {
            mu[i] = sm[i] * (1.0f / 128.0f);
            const float var = sq[i] * (1.0f / 128.0f) - mu[i] * mu[i];
            rs[i] = rsqrtf(var + 1e-5f);
        }
        // normalize + gelu -> hbuf (own rows only; no cross-wave dependency)
#pragma unroll
        for (int nt = 0; nt < 8; ++nt) {
            const float gv  = g1[f * HD + nt * 16 + n];
            const float bev = be1[f * HD + nt * 16 + n];
#pragma unroll
            for (int i = 0; i < 4; ++i) {
                const float v = (hc[nt][i] - mu[i]) * rs[i] * gv + bev;
                hbuf[(wrow + q * 4 + i) * 136 + nt * 16 + n] = f2bf(gelu_fast(v));
            }
        }
        __syncthreads();   // barrier2: all waves done reading wbuf (W1/Wr)

        // ---- stage W2[f] (32KB) ----
        {
            const unsigned short* gw2 = W2s + (size_t)f * 16384;
#pragma unroll
            for (int i = 0; i < 8; ++i) {
                const int chunk = i * 4 + wv;
                load16_lds(gw2 + chunk * 512 + ln * 8, wbuf + chunk * 512);
            }
        }
        __syncthreads();   // barrier3: W2 visible (vmcnt drained)

        // ---- GEMM2: A = h1g frags (K=128) ----
        s16x8 A2[4];
#pragma unroll
        for (int c = 0; c < 4; ++c)
            A2[c] = *(const s16x8*)&hbuf[(wrow + n) * 136 + c * 32 + q * 8];
        f32x4 h2[8];
#pragma unroll
        for (int nt = 0; nt < 8; ++nt) {
            f32x4 z = f32x4{0.f, 0.f, 0.f, 0.f};
#pragma unroll
            for (int c = 0; c < 4; ++c) {
                const s16x8 bF = *(const s16x8*)&wbuf[(nt * 16 + c * 4) * 128 + ln * 8];
                z = __builtin_amdgcn_mfma_f32_16x16x32_bf16(A2[c], bF, z, 0, 0, 0);
            }
            h2[nt] = z;
        }

        // ---- LN2 (+b2), gelu, fold residual + attention weight into agg ----
        const float wf = wsoft[f];
#pragma unroll
        for (int i = 0; i < 4; ++i) { sm[i] = 0.f; sq[i] = 0.f; }
#pragma unroll
        for (int nt = 0; nt < 8; ++nt) {
            const float bv = b2[f * HD + nt * 16 + n];
#pragma unroll
            for (int i = 0; i < 4; ++i) {
                const float v = h2[nt][i] + bv;
                h2[nt][i] = v; sm[i] += v; sq[i] += v * v;
            }
        }
#pragma unroll
        for (int s = 1; s <= 8; s <<= 1) {
#pragma unroll
            for (int i = 0; i < 4; ++i) {
                sm[i] += __shfl_xor(sm[i], s, 64);
                sq[i] += __shfl_xor(sq[i], s, 64);
            }
        }
#pragma unroll
        for (int i = 0; i < 4; ++i) {
            mu[i] = sm[i] * (1.0f / 128.0f);
            const float var = sq[i] * (1.0f / 128.0f) - mu[i] * mu[i];
            rs[i] = rsqrtf(var + 1e-5f);
        }
#pragma unroll
        for (int nt = 0; nt < 8; ++nt) {
            const float gv  = g2[f * HD + nt * 16 + n];
            const float bev = be2[f * HD + nt * 16 + n];
            const float brv = br[f * HD + nt * 16 + n];
#pragma unroll
            for (int i = 0; i < 4; ++i) {
                const float v = (h2[nt][i] - mu[i]) * rs[i] * gv + bev;
                agg[nt][i] += wf * (gelu_fast(v) + 0.1f * (rc[nt][i] + brv));
            }
        }
    }

    // ---- epilogue: partial agg (per feature-group) to workspace ----
    float* ap = aggP + (size_t)fg * BQ * HD;
#pragma unroll
    for (int nt = 0; nt < 8; ++nt) {
#pragma unroll
        for (int i = 0; i < 4; ++i) {
            ap[(size_t)(b0 + wrow + q * 4 + i) * HD + nt * 16 + n] = agg[nt][i];
        }
    }
}

// ---------------- mixture-beta head: one wave per batch row ----------------
__global__ void __launch_bounds__(256) nam_head(
    const float* __restrict__ agg0, const float* __restrict__ agg1,
    const float* __restrict__ bias,
    const float* __restrict__ Wpi, const float* __restrict__ bpi,
    const float* __restrict__ Wa,  const float* __restrict__ ba,
    const float* __restrict__ Wb,  const float* __restrict__ bb,
    float* __restrict__ out)
{
    const int gid  = blockIdx.x * blockDim.x + threadIdx.x;
    const int row  = gid >> 6;
    const int lane = threadIdx.x & 63;
    if (row >= BQ) return;

    const float2 p0 = ((const float2*)(agg0 + (size_t)row * HD))[lane];
    const float2 p1 = ((const float2*)(agg1 + (size_t)row * HD))[lane];
    const float2 bs = ((const float2*)bias)[lane];
    const float ax = p0.x + p1.x + bs.x;
    const float ay = p0.y + p1.y + bs.y;

    const float2* wp = (const float2*)Wpi;
    const float2* wa = (const float2*)Wa;
    const float2* wb = (const float2*)Wb;
    const float2 p01 = wp[lane * 3], p23 = wp[lane * 3 + 1], p45 = wp[lane * 3 + 2];
    const float2 a01 = wa[lane * 3], a23 = wa[lane * 3 + 1], a45 = wa[lane * 3 + 2];
    const float2 b01 = wb[lane * 3], b23 = wb[lane * 3 + 1], b45 = wb[lane * 3 + 2];

    float ppi0 = ax * p01.x + ay * p23.y;
    float ppi1 = ax * p01.y + ay * p45.x;
    float ppi2 = ax * p23.x + ay * p45.y;
    float pa0  = ax * a01.x + ay * a23.y;
    float pa1  = ax * a01.y + ay * a45.x;
    float pa2  = ax * a23.x + ay * a45.y;
    float pb0  = ax * b01.x + ay * b23.y;
    float pb1  = ax * b01.y + ay * b45.x;
    float pb2  = ax * b23.x + ay * b45.y;

#pragma unroll
    for (int s = 32; s >= 1; s >>= 1) {
        ppi0 += __shfl_xor(ppi0, s, 64);
        ppi1 += __shfl_xor(ppi1, s, 64);
        ppi2 += __shfl_xor(ppi2, s, 64);
        pa0  += __shfl_xor(pa0,  s, 64);
        pa1  += __shfl_xor(pa1,  s, 64);
        pa2  += __shfl_xor(pa2,  s, 64);
        pb0  += __shfl_xor(pb0,  s, 64);
        pb1  += __shfl_xor(pb1,  s, 64);
        pb2  += __shfl_xor(pb2,  s, 64);
    }

    if (lane == 0) {
        const float z0 = ppi0 + bpi[0], z1 = ppi1 + bpi[1], z2 = ppi2 + bpi[2];
        const float mz = fmaxf(z0, fmaxf(z1, z2));
        const float e0 = expf(z0 - mz), e1 = expf(z1 - mz), e2 = expf(z2 - mz);
        const float es = e0 + e1 + e2;

        const float al0 = fminf(fmaxf(softplus_stable(pa0 + ba[0]) + 1.01f, 1.01f), 100.0f);
        const float al1 = fminf(fmaxf(softplus_stable(pa1 + ba[1]) + 1.01f, 1.01f), 100.0f);
        const float al2 = fminf(fmaxf(softplus_stable(pa2 + ba[2]) + 1.01f, 1.01f), 100.0f);
        const float bt0 = fminf(fmaxf(softplus_stable(pb0 + bb[0]) + 1.01f, 1.01f), 100.0f);
        const float bt1 = fminf(fmaxf(softplus_stable(pb1 + bb[1]) + 1.01f, 1.01f), 100.0f);
        const float bt2 = fminf(fmaxf(softplus_stable(pb2 + bb[2]) + 1.01f, 1.01f), 100.0f);

        const float pred = (e0 * (al0 / (al0 + bt0))
                          + e1 * (al1 / (al1 + bt1))
                          + e2 * (al2 / (al2 + bt2))) / es;
        out[row] = fminf(fmaxf(pred, 0.001f), 0.999f);
    }
}

extern "C" void kernel_launch(void* const* d_in, const int* in_sizes, int n_in,
                              void* d_out, int out_size, void* d_ws, size_t ws_size,
                              hipStream_t stream) {
    const float* x          = (const float*)d_in[0];
    const float* centers    = (const float*)d_in[1];
    const float* log_widths = (const float*)d_in[2];
    const float* W1   = (const float*)d_in[3];
    const float* b1   = (const float*)d_in[4];
    const float* g1   = (const float*)d_in[5];
    const float* be1  = (const float*)d_in[6];
    const float* W2   = (const float*)d_in[7];
    const float* b2   = (const float*)d_in[8];
    const float* g2   = (const float*)d_in[9];
    const float* be2  = (const float*)d_in[10];
    const float* Wr   = (const float*)d_in[11];
    const float* br   = (const float*)d_in[12];
    const float* att  = (const float*)d_in[13];
    const float* bias = (const float*)d_in[14];
    const float* Wpi  = (const float*)d_in[15];
    const float* bpi  = (const float*)d_in[16];
    const float* Wa   = (const float*)d_in[17];
    const float* ba   = (const float*)d_in[18];
    const float* Wb   = (const float*)d_in[19];
    const float* bb   = (const float*)d_in[20];

    // ---- workspace layout (byte offsets, all 16B-aligned) ----
    char* ws = (char*)d_ws;
    float*          wsoft = (float*)(ws + 0);                    //   256 B
    float*          rwid  = (float*)(ws + 4096);                 //  16 KB
    float*          xT    = (float*)(ws + 20480);                //   4 MB
    float*          aggP  = (float*)(ws + 4214784);              //  16 MB (2 partials)
    unsigned short* W1s   = (unsigned short*)(ws + 20992000);    //   1 MB
    unsigned short* Wrs   = (unsigned short*)(ws + 22040576);    //   1 MB
    unsigned short* W2s   = (unsigned short*)(ws + 23089152);    //   2 MB

    nam_att_softmax<<<1, 64, 0, stream>>>(att, wsoft);
    nam_rwid<<<16, 256, 0, stream>>>(log_widths, rwid);
    nam_xtr<<<4096, 256, 0, stream>>>(x, xT);
    nam_swz<<<256, 256, 0, stream>>>(W1, W1s, NBQ);
    nam_swz<<<256, 256, 0, stream>>>(Wr, Wrs, NBQ);
    nam_swz<<<512, 256, 0, stream>>>(W2, W2s, HD);

    nam_main<<<512, 256, 0, stream>>>(centers, rwid, xT, W1s, Wrs, W2s,
                                      b1, g1, be1, b2, g2, be2, br, wsoft, aggP);

    nam_head<<<BQ / 4, 256, 0, stream>>>(aggP, aggP + (size_t)BQ * HD, bias,
                                         Wpi, bpi, Wa, ba, Wb, bb, (float*)d_out);
}

// Round 3
// 455.337 us; speedup vs baseline: 93.1835x; 1.0440x over previous
//
#include <hip/hip_runtime.h>
#include <math.h>

// Problem constants (fixed by the reference).
#define BQ   16384
#define FQ   64
#define NBQ  64
#define HD   128
#define FG   4       // feature groups
#define FPG  16      // features per group

typedef __attribute__((ext_vector_type(8))) short s16x8;   // 8 bf16 (4 VGPRs)
typedef __attribute__((ext_vector_type(4))) float f32x4;   // MFMA C/D

// round-to-nearest-even fp32 -> bf16 (used in weight prep only)
__device__ __forceinline__ unsigned short f2bf(float x) {
    unsigned int u = __float_as_uint(x);
    return (unsigned short)((u + 0x7FFFu + ((u >> 16) & 1u)) >> 16);
}
// truncation fp32 -> bf16 (activations; 1 inst, often folds into d16_hi store)
__device__ __forceinline__ unsigned short bftr(float x) {
    return (unsigned short)(__float_as_uint(x) >> 16);
}

__device__ __forceinline__ float softplus_stable(float v) {
    return (v > 0.0f) ? (v + log1pf(expf(-v))) : log1pf(expf(v));
}

// tanh-form gelu as sigmoid: gelu(v) = v / (1 + exp(-(1.5957691 v + 0.07135481 v^3)))
__device__ __forceinline__ f32x4 gelu4(f32x4 v) {
    const f32x4 v2 = v * v;
    const f32x4 tt = v2 * (-0.07135481f) + (-1.5957691f);
    const f32x4 s  = v * tt;                  // s = -(k)
    f32x4 r;
    r[0] = __fdividef(v[0], 1.0f + __expf(s[0]));
    r[1] = __fdividef(v[1], 1.0f + __expf(s[1]));
    r[2] = __fdividef(v[2], 1.0f + __expf(s[2]));
    r[3] = __fdividef(v[3], 1.0f + __expf(s[3]));
    return r;
}

// async 16B global->LDS
__device__ __forceinline__ void load16_lds(const unsigned short* g, unsigned short* l) {
    __builtin_amdgcn_global_load_lds(
        (const __attribute__((address_space(1))) unsigned int*)(uintptr_t)g,
        (__attribute__((address_space(3))) unsigned int*)(uintptr_t)l,
        16, 0, 0);
}

// ---------------- prep A (1 block): att softmax, rbf coeffs, folded head bias ----
__global__ void __launch_bounds__(256) prep_small(
    const float* __restrict__ att, const float* __restrict__ log_widths,
    const float* __restrict__ centers, const float* __restrict__ br,
    const float* __restrict__ bias,
    float* __restrict__ wsoft, float* __restrict__ crw, float* __restrict__ rbias)
{
    __shared__ float ws[64];
    const int t = threadIdx.x;
    if (t < 64) {
        float v = att[t];
        float m = v;
#pragma unroll
        for (int s = 32; s >= 1; s >>= 1) m = fmaxf(m, __shfl_xor(m, s, 64));
        float e = expf(v - m);
        float ssum = e;
#pragma unroll
        for (int s = 32; s >= 1; s >>= 1) ssum += __shfl_xor(ssum, s, 64);
        const float w = e / ssum;
        ws[t] = w;
        wsoft[t] = w;
    }
    __syncthreads();
    // rbf coeffs: crw[i] = {1/width, -center/width}
    for (int i = t; i < FQ * NBQ; i += 256) {
        float lw = fminf(fmaxf(log_widths[i], -5.0f), 5.0f);
        const float rw = 1.0f / (expf(lw) + 0.1f);
        ((float2*)crw)[i] = make_float2(rw, -centers[i] * rw);
    }
    // folded head bias: rbias[c] = bias[c] + sum_f 0.1*w[f]*br[f][c]
    if (t < HD) {
        float s = bias[t];
        for (int f = 0; f < FQ; ++f) s += 0.1f * ws[f] * br[f * HD + t];
        rbias[t] = s;
    }
}

// ---------------- prep B: pack LN params 8-wide per (f,c) ----------------
// Pk[(f*128+c)*8] = {b1,g1,be1,0, b2,g2,be2,0}
__global__ void __launch_bounds__(256) prep_pack(
    const float* __restrict__ b1, const float* __restrict__ g1, const float* __restrict__ be1,
    const float* __restrict__ b2, const float* __restrict__ g2, const float* __restrict__ be2,
    float* __restrict__ Pk)
{
    const int id = blockIdx.x * 256 + threadIdx.x;
    if (id >= FQ * HD) return;
    ((float4*)Pk)[id * 2]     = make_float4(b1[id], g1[id], be1[id], 0.0f);
    ((float4*)Pk)[id * 2 + 1] = make_float4(b2[id], g2[id], be2[id], 0.0f);
}

// ---------------- prep C: weight convert + swizzle (all three, merged) --------
__global__ void __launch_bounds__(256) prep_swz(
    const float* __restrict__ W1, const float* __restrict__ Wr, const float* __restrict__ W2,
    unsigned short* __restrict__ W1s, unsigned short* __restrict__ Wrs,
    unsigned short* __restrict__ W2s)
{
    const int gid = blockIdx.x * 256 + threadIdx.x;
    const float* W; unsigned short* dst; int K, id;
    if (gid < 65536)       { W = W1; dst = W1s; K = 64;  id = gid; }
    else if (gid < 131072) { W = Wr; dst = Wrs; K = 64;  id = gid - 65536; }
    else                   { W = W2; dst = W2s; K = 128; id = gid - 131072; }
    const int KB = K >> 3;
    const int nn = id & 15;
    const int kb = (id >> 4) % KB;
    const int nt = ((id >> 4) / KB) & 7;
    const int f  = id / (KB * 16 * 8);
    const float* src = W + ((size_t)f * K + kb * 8) * HD + nt * 16 + nn;
    s16x8 o;
#pragma unroll
    for (int j = 0; j < 8; ++j) o[j] = (short)f2bf(src[(size_t)j * HD]);
    *(s16x8*)(dst + (size_t)f * K * HD + ((size_t)(nt * KB + kb) * 16 + nn) * 8) = o;
}

// ---------------- prep D: LDS-tiled x transpose ----------------
__global__ void __launch_bounds__(256) prep_xtr(const float* __restrict__ x,
                                                float* __restrict__ xT) {
    __shared__ float tile[64][65];
    const int t  = threadIdx.x;
    const int b0 = blockIdx.x * 64;
    {
        const int row = t & 63, cg = (t >> 6) * 16;
        const float4* src = (const float4*)(x + (size_t)(b0 + row) * FQ + cg);
#pragma unroll
        for (int i = 0; i < 4; ++i) {
            const float4 v = src[i];
            tile[row][cg + i * 4 + 0] = v.x;
            tile[row][cg + i * 4 + 1] = v.y;
            tile[row][cg + i * 4 + 2] = v.z;
            tile[row][cg + i * 4 + 3] = v.w;
        }
    }
    __syncthreads();
    {
        const int f = t >> 2, r0 = (t & 3) * 16;
        float* dst = xT + (size_t)f * BQ + b0 + r0;
#pragma unroll
        for (int i = 0; i < 16; ++i) dst[i] = tile[r0 + i][f];
    }
}

// ---------------- fused MFMA NAM body ----------------
// grid 1024 = 4 fgroups x 256 row-tiles(M=64). 256 threads (4 waves, 16 rows each).
__global__ void __launch_bounds__(256, 3) nam_main(
    const float* __restrict__ crw,
    const float* __restrict__ xT,
    const unsigned short* __restrict__ W1s,
    const unsigned short* __restrict__ Wrs,
    const unsigned short* __restrict__ W2s,
    const float* __restrict__ Pk,
    const float* __restrict__ wsoft,
    float* __restrict__ agg)
{
    __shared__ __align__(16) unsigned short wbuf[16384];   // 32KB: W1+Wr, then W2
    __shared__ __align__(16) unsigned short hbuf[64 * 136]; // 17KB: rbf tile aliased w/ h1g

    const int t    = threadIdx.x;
    const int ln   = t & 63;
    const int wv   = t >> 6;
    const int n    = ln & 15;
    const int q    = ln >> 4;
    const int wrow = wv * 16;
    const int fg   = blockIdx.x & 3;
    const int rb   = blockIdx.x >> 2;
    const int b0   = rb * 64;

    f32x4 acc[8];
#pragma unroll
    for (int nt = 0; nt < 8; ++nt) acc[nt] = f32x4{0.f, 0.f, 0.f, 0.f};

    for (int ff = 0; ff < FPG; ++ff) {
        const int f = fg * FPG + ((ff + rb) & (FPG - 1));   // decorrelated order
        __syncthreads();   // B0: prev iter's wbuf(W2)/hbuf readers done

        // ---- stage W1[f]+Wr[f] (32KB) async ----
        {
            const unsigned short* gw1 = W1s + (size_t)f * 8192;
            const unsigned short* gwr = Wrs + (size_t)f * 8192;
#pragma unroll
            for (int i = 0; i < 8; ++i) {
                const int chunk = i * 4 + wv;
                const unsigned short* src = (chunk < 16) ? (gw1 + chunk * 512)
                                                         : (gwr + (chunk - 16) * 512);
                load16_lds(src + ln * 8, wbuf + chunk * 512);
            }
        }

        // ---- rbf tile -> hbuf cols 0..63 (bf16 trunc via v_perm) ----
        {
            const int row = t & 63;
            const int ng  = t >> 6;
            const float xv = xT[(size_t)f * BQ + b0 + row];
            const float4* c4 = (const float4*)(crw + ((size_t)f * NBQ + ng * 16) * 2);
            float e[16];
#pragma unroll
            for (int i2 = 0; i2 < 8; ++i2) {
                const float4 cc = c4[i2];                // {rw0,ncw0, rw1,ncw1}
                const float d0 = fmaf(xv, cc.x, cc.y);
                const float d1 = fmaf(xv, cc.z, cc.w);
                e[i2 * 2]     = __expf(-0.5f * d0 * d0);
                e[i2 * 2 + 1] = __expf(-0.5f * d1 * d1);
            }
            unsigned int p[8];
#pragma unroll
            for (int i2 = 0; i2 < 8; ++i2)
                p[i2] = __builtin_amdgcn_perm(__float_as_uint(e[2 * i2 + 1]),
                                              __float_as_uint(e[2 * i2]), 0x07060302u);
            *(int4*)&hbuf[row * 136 + ng * 16]     = make_int4(p[0], p[1], p[2], p[3]);
            *(int4*)&hbuf[row * 136 + ng * 16 + 8] = make_int4(p[4], p[5], p[6], p[7]);
        }
        __syncthreads();   // B1: DMA drained + rbf visible

        // ---- GEMM1 (h1) + GEMMr (res): A = rbf frags, K=64 ----
        const s16x8 a0 = *(const s16x8*)&hbuf[(wrow + n) * 136 + q * 8];
        const s16x8 a1 = *(const s16x8*)&hbuf[(wrow + n) * 136 + 32 + q * 8];
        f32x4 hc[8], rc[8];
#pragma unroll
        for (int nt = 0; nt < 8; ++nt) {
            const s16x8 bA = *(const s16x8*)&wbuf[(nt * 8 + 0) * 128 + ln * 8];
            const s16x8 bB = *(const s16x8*)&wbuf[(nt * 8 + 4) * 128 + ln * 8];
            f32x4 z = f32x4{0.f, 0.f, 0.f, 0.f};
            z = __builtin_amdgcn_mfma_f32_16x16x32_bf16(a0, bA, z, 0, 0, 0);
            z = __builtin_amdgcn_mfma_f32_16x16x32_bf16(a1, bB, z, 0, 0, 0);
            hc[nt] = z;
            const s16x8 cA = *(const s16x8*)&wbuf[8192 + (nt * 8 + 0) * 128 + ln * 8];
            const s16x8 cB = *(const s16x8*)&wbuf[8192 + (nt * 8 + 4) * 128 + ln * 8];
            f32x4 y = f32x4{0.f, 0.f, 0.f, 0.f};
            y = __builtin_amdgcn_mfma_f32_16x16x32_bf16(a0, cA, y, 0, 0, 0);
            y = __builtin_amdgcn_mfma_f32_16x16x32_bf16(a1, cB, y, 0, 0, 0);
            rc[nt] = y;
        }
        __syncthreads();   // B2: all waves done reading W1/Wr from wbuf

        // ---- stage W2[f] (32KB) async — overlaps the LN1 VALU work below ----
        {
            const unsigned short* gw2 = W2s + (size_t)f * 16384;
#pragma unroll
            for (int i = 0; i < 8; ++i) {
                const int chunk = i * 4 + wv;
                load16_lds(gw2 + chunk * 512 + ln * 8, wbuf + chunk * 512);
            }
        }

        // ---- LN1 (+b1) in registers, gelu, h1g -> hbuf ----
        const size_t pkb = ((size_t)f * HD + n) * 8;
        f32x4 sm = {0.f, 0.f, 0.f, 0.f}, sq = {0.f, 0.f, 0.f, 0.f};
#pragma unroll
        for (int nt = 0; nt < 8; ++nt) {
            const float4 pA = *(const float4*)(Pk + pkb + nt * 128);
            const f32x4 v = hc[nt] + pA.x;
            hc[nt] = v; sm += v; sq += v * v;
        }
#pragma unroll
        for (int s = 1; s <= 8; s <<= 1) {
#pragma unroll
            for (int i = 0; i < 4; ++i) {
                sm[i] += __shfl_xor(sm[i], s, 64);
                sq[i] += __shfl_xor(sq[i], s, 64);
            }
        }
        f32x4 mu4 = sm * (1.0f / 128.0f);
        f32x4 var4 = sq * (1.0f / 128.0f) - mu4 * mu4;
        f32x4 rs4;
#pragma unroll
        for (int i = 0; i < 4; ++i) rs4[i] = rsqrtf(var4[i] + 1e-5f);
#pragma unroll
        for (int nt = 0; nt < 8; ++nt) {
            const float4 pA = *(const float4*)(Pk + pkb + nt * 128);
            const f32x4 sg = rs4 * pA.y;
            const f32x4 y  = (hc[nt] - mu4) * sg + pA.z;
            const f32x4 z  = gelu4(y);
            unsigned short* hp = hbuf + (wrow + q * 4) * 136 + nt * 16 + n;
            hp[0]   = bftr(z[0]);
            hp[136] = bftr(z[1]);
            hp[272] = bftr(z[2]);
            hp[408] = bftr(z[3]);
        }
        __syncthreads();   // B3: W2 DMA drained; hbuf h1g ready

        // ---- GEMM2: A = h1g frags (K=128) ----
        s16x8 A2[4];
#pragma unroll
        for (int c = 0; c < 4; ++c)
            A2[c] = *(const s16x8*)&hbuf[(wrow + n) * 136 + c * 32 + q * 8];
        f32x4 h2[8];
#pragma unroll
        for (int nt = 0; nt < 8; ++nt) {
            f32x4 z = f32x4{0.f, 0.f, 0.f, 0.f};
#pragma unroll
            for (int c = 0; c < 4; ++c) {
                const s16x8 bF = *(const s16x8*)&wbuf[(nt * 16 + c * 4) * 128 + ln * 8];
                z = __builtin_amdgcn_mfma_f32_16x16x32_bf16(A2[c], bF, z, 0, 0, 0);
            }
            h2[nt] = z;
        }

        // ---- LN2 (+b2), gelu, fold residual + attention weight into acc ----
        sm = f32x4{0.f, 0.f, 0.f, 0.f}; sq = f32x4{0.f, 0.f, 0.f, 0.f};
#pragma unroll
        for (int nt = 0; nt < 8; ++nt) {
            const float4 pB = *(const float4*)(Pk + pkb + nt * 128 + 4);
            const f32x4 v = h2[nt] + pB.x;
            h2[nt] = v; sm += v; sq += v * v;
        }
#pragma unroll
        for (int s = 1; s <= 8; s <<= 1) {
#pragma unroll
            for (int i = 0; i < 4; ++i) {
                sm[i] += __shfl_xor(sm[i], s, 64);
                sq[i] += __shfl_xor(sq[i], s, 64);
            }
        }
        mu4 = sm * (1.0f / 128.0f);
        var4 = sq * (1.0f / 128.0f) - mu4 * mu4;
#pragma unroll
        for (int i = 0; i < 4; ++i) rs4[i] = rsqrtf(var4[i] + 1e-5f);
        const float wf   = wsoft[f];
        const float wf01 = 0.1f * wf;
#pragma unroll
        for (int nt = 0; nt < 8; ++nt) {
            const float4 pB = *(const float4*)(Pk + pkb + nt * 128 + 4);
            const f32x4 sg = rs4 * pB.y;
            const f32x4 y  = (h2[nt] - mu4) * sg + pB.z;
            acc[nt] = gelu4(y) * wf + acc[nt];
            acc[nt] = rc[nt] * wf01 + acc[nt];
        }
    }

    // ---- epilogue: atomic accumulate into shared agg ----
    float* ap = agg + (size_t)(b0 + wrow + q * 4) * HD + n;
#pragma unroll
    for (int nt = 0; nt < 8; ++nt) {
#pragma unroll
        for (int i = 0; i < 4; ++i) {
            atomicAdd(ap + (size_t)i * HD + nt * 16, acc[nt][i]);
        }
    }
}

// ---------------- mixture-beta head: one wave per batch row ----------------
__global__ void __launch_bounds__(256) nam_head(
    const float* __restrict__ agg, const float* __restrict__ rbias,
    const float* __restrict__ Wpi, const float* __restrict__ bpi,
    const float* __restrict__ Wa,  const float* __restrict__ ba,
    const float* __restrict__ Wb,  const float* __restrict__ bb,
    float* __restrict__ out)
{
    const int gid  = blockIdx.x * blockDim.x + threadIdx.x;
    const int row  = gid >> 6;
    const int lane = threadIdx.x & 63;
    if (row >= BQ) return;

    const float2 p  = ((const float2*)(agg + (size_t)row * HD))[lane];
    const float2 rb = ((const float2*)rbias)[lane];
    const float ax = p.x + rb.x;
    const float ay = p.y + rb.y;

    const float2* wp = (const float2*)Wpi;
    const float2* wa = (const float2*)Wa;
    const float2* wb = (const float2*)Wb;
    const float2 p01 = wp[lane * 3], p23 = wp[lane * 3 + 1], p45 = wp[lane * 3 + 2];
    const float2 a01 = wa[lane * 3], a23 = wa[lane * 3 + 1], a45 = wa[lane * 3 + 2];
    const float2 b01 = wb[lane * 3], b23 = wb[lane * 3 + 1], b45 = wb[lane * 3 + 2];

    float ppi0 = ax * p01.x + ay * p23.y;
    float ppi1 = ax * p01.y + ay * p45.x;
    float ppi2 = ax * p23.x + ay * p45.y;
    float pa0  = ax * a01.x + ay * a23.y;
    float pa1  = ax * a01.y + ay * a45.x;
    float pa2  = ax * a23.x + ay * a45.y;
    float pb0  = ax * b01.x + ay * b23.y;
    float pb1  = ax * b01.y + ay * b45.x;
    float pb2  = ax * b23.x + ay * b45.y;

#pragma unroll
    for (int s = 32; s >= 1; s >>= 1) {
        ppi0 += __shfl_xor(ppi0, s, 64);
        ppi1 += __shfl_xor(ppi1, s, 64);
        ppi2 += __shfl_xor(ppi2, s, 64);
        pa0  += __shfl_xor(pa0,  s, 64);
        pa1  += __shfl_xor(pa1,  s, 64);
        pa2  += __shfl_xor(pa2,  s, 64);
        pb0  += __shfl_xor(pb0,  s, 64);
        pb1  += __shfl_xor(pb1,  s, 64);
        pb2  += __shfl_xor(pb2,  s, 64);
    }

    if (lane == 0) {
        const float z0 = ppi0 + bpi[0], z1 = ppi1 + bpi[1], z2 = ppi2 + bpi[2];
        const float mz = fmaxf(z0, fmaxf(z1, z2));
        const float e0 = expf(z0 - mz), e1 = expf(z1 - mz), e2 = expf(z2 - mz);
        const float es = e0 + e1 + e2;

        const float al0 = fminf(fmaxf(softplus_stable(pa0 + ba[0]) + 1.01f, 1.01f), 100.0f);
        const float al1 = fminf(fmaxf(softplus_stable(pa1 + ba[1]) + 1.01f, 1.01f), 100.0f);
        const float al2 = fminf(fmaxf(softplus_stable(pa2 + ba[2]) + 1.01f, 1.01f), 100.0f);
        const float bt0 = fminf(fmaxf(softplus_stable(pb0 + bb[0]) + 1.01f, 1.01f), 100.0f);
        const float bt1 = fminf(fmaxf(softplus_stable(pb1 + bb[1]) + 1.01f, 1.01f), 100.0f);
        const float bt2 = fminf(fmaxf(softplus_stable(pb2 + bb[2]) + 1.01f, 1.01f), 100.0f);

        const float pred = (e0 * (al0 / (al0 + bt0))
                          + e1 * (al1 / (al1 + bt1))
                          + e2 * (al2 / (al2 + bt2))) / es;
        out[row] = fminf(fmaxf(pred, 0.001f), 0.999f);
    }
}

extern "C" void kernel_launch(void* const* d_in, const int* in_sizes, int n_in,
                              void* d_out, int out_size, void* d_ws, size_t ws_size,
                              hipStream_t stream) {
    const float* x          = (const float*)d_in[0];
    const float* centers    = (const float*)d_in[1];
    const float* log_widths = (const float*)d_in[2];
    const float* W1   = (const float*)d_in[3];
    const float* b1   = (const float*)d_in[4];
    const float* g1   = (const float*)d_in[5];
    const float* be1  = (const float*)d_in[6];
    const float* W2   = (const float*)d_in[7];
    const float* b2   = (const float*)d_in[8];
    const float* g2   = (const float*)d_in[9];
    const float* be2  = (const float*)d_in[10];
    const float* Wr   = (const float*)d_in[11];
    const float* br   = (const float*)d_in[12];
    const float* att  = (const float*)d_in[13];
    const float* bias = (const float*)d_in[14];
    const float* Wpi  = (const float*)d_in[15];
    const float* bpi  = (const float*)d_in[16];
    const float* Wa   = (const float*)d_in[17];
    const float* ba   = (const float*)d_in[18];
    const float* Wb   = (const float*)d_in[19];
    const float* bb   = (const float*)d_in[20];

    // ---- workspace layout (byte offsets, 16B-aligned; top = ~17.1 MB) ----
    char* ws = (char*)d_ws;
    float*          wsoft = (float*)(ws + 0);          //   256 B
    float*          rbias = (float*)(ws + 1024);       //   512 B
    float*          crw   = (float*)(ws + 8192);       //  32 KB (float2[4096])
    float*          Pk    = (float*)(ws + 65536);      // 256 KB
    float*          xT    = (float*)(ws + 327680);     //   4 MB
    unsigned short* W1s   = (unsigned short*)(ws + 4521984);   // 1 MB
    unsigned short* Wrs   = (unsigned short*)(ws + 5570560);   // 1 MB
    unsigned short* W2s   = (unsigned short*)(ws + 6619136);   // 2 MB
    float*          agg   = (float*)(ws + 8716288);    //   8 MB

    prep_small<<<1, 256, 0, stream>>>(att, log_widths, centers, br, bias,
                                      wsoft, crw, rbias);
    prep_pack<<<32, 256, 0, stream>>>(b1, g1, be1, b2, g2, be2, Pk);
    prep_swz<<<1024, 256, 0, stream>>>(W1, Wr, W2, W1s, Wrs, W2s);
    prep_xtr<<<256, 256, 0, stream>>>(x, xT);
    hipMemsetAsync(agg, 0, (size_t)BQ * HD * sizeof(float), stream);

    nam_main<<<256 * FG, 256, 0, stream>>>(crw, xT, W1s, Wrs, W2s, Pk, wsoft, agg);

    nam_head<<<BQ / 4, 256, 0, stream>>>(agg, rbias, Wpi, bpi, Wa, ba, Wb, bb,
                                         (float*)d_out);
}

// Round 4
// 434.193 us; speedup vs baseline: 97.7213x; 1.0487x over previous
//
#include <hip/hip_runtime.h>
#include <math.h>

// Problem constants (fixed by the reference).
#define BQ   16384
#define FQ   64
#define NBQ  64
#define HD   128
#define FG   4       // feature groups
#define FPG  16      // features per group
#define MT   128     // batch rows per block
#define NT   512     // threads (8 waves)

typedef __attribute__((ext_vector_type(8))) short s16x8;   // 8 bf16 (4 VGPRs)
typedef __attribute__((ext_vector_type(4))) float f32x4;   // MFMA C/D

// round-to-nearest-even fp32 -> bf16 (weight prep only)
__device__ __forceinline__ unsigned short f2bf(float x) {
    unsigned int u = __float_as_uint(x);
    return (unsigned short)((u + 0x7FFFu + ((u >> 16) & 1u)) >> 16);
}
// truncation fp32 -> bf16 (activations)
__device__ __forceinline__ unsigned short bftr(float x) {
    return (unsigned short)(__float_as_uint(x) >> 16);
}

__device__ __forceinline__ float softplus_stable(float v) {
    return (v > 0.0f) ? (v + log1pf(expf(-v))) : log1pf(expf(v));
}

// tanh-form gelu as sigmoid: gelu(v) = v / (1 + exp(-(1.5957691 v + 0.07135481 v^3)))
__device__ __forceinline__ f32x4 gelu4(f32x4 v) {
    const f32x4 v2 = v * v;
    const f32x4 tt = v2 * (-0.07135481f) + (-1.5957691f);
    const f32x4 s  = v * tt;
    f32x4 r;
    r[0] = __fdividef(v[0], 1.0f + __expf(s[0]));
    r[1] = __fdividef(v[1], 1.0f + __expf(s[1]));
    r[2] = __fdividef(v[2], 1.0f + __expf(s[2]));
    r[3] = __fdividef(v[3], 1.0f + __expf(s[3]));
    return r;
}

// sum across the 16 lanes of a DPP row (our LN reduce domain) — no LDS ops.
__device__ __forceinline__ float dppsum16(float x) {
    int t;
    t = __builtin_amdgcn_update_dpp(0, __float_as_int(x), 0xB1,  0xF, 0xF, true); // quad_perm [1,0,3,2]
    x += __int_as_float(t);
    t = __builtin_amdgcn_update_dpp(0, __float_as_int(x), 0x4E,  0xF, 0xF, true); // quad_perm [2,3,0,1]
    x += __int_as_float(t);
    t = __builtin_amdgcn_update_dpp(0, __float_as_int(x), 0x125, 0xF, 0xF, true); // row_ror:4
    x += __int_as_float(t);
    t = __builtin_amdgcn_update_dpp(0, __float_as_int(x), 0x129, 0xF, 0xF, true); // row_ror:8
    x += __int_as_float(t);
    return x;
}

// async 16B global->LDS
__device__ __forceinline__ void load16_lds(const unsigned short* g, unsigned short* l) {
    __builtin_amdgcn_global_load_lds(
        (const __attribute__((address_space(1))) unsigned int*)(uintptr_t)g,
        (__attribute__((address_space(3))) unsigned int*)(uintptr_t)l,
        16, 0, 0);
}

// h1g LDS addressing: stride 128 shorts, XOR swizzle to spread banks.
__device__ __forceinline__ int hofs(int row, int col) {
    return row * 128 + (col ^ (((row >> 2) & 3) << 4));
}

// ---------------- prep A: softmax + rbf coeffs + folded head bias + LN packs ----
__global__ void __launch_bounds__(256) prep_misc(
    const float* __restrict__ att, const float* __restrict__ log_widths,
    const float* __restrict__ centers, const float* __restrict__ br,
    const float* __restrict__ bias,
    const float* __restrict__ b1, const float* __restrict__ g1, const float* __restrict__ be1,
    const float* __restrict__ b2, const float* __restrict__ g2, const float* __restrict__ be2,
    float* __restrict__ wsoft, float* __restrict__ crw2, float* __restrict__ rbias,
    float* __restrict__ Pk)
{
    const int t = threadIdx.x;
    if (blockIdx.x == 0) {
        __shared__ float ws[64];
        if (t < 64) {
            float v = att[t];
            float m = v;
#pragma unroll
            for (int s = 32; s >= 1; s >>= 1) m = fmaxf(m, __shfl_xor(m, s, 64));
            float e = expf(v - m);
            float ssum = e;
#pragma unroll
            for (int s = 32; s >= 1; s >>= 1) ssum += __shfl_xor(ssum, s, 64);
            const float w = e / ssum;
            ws[t] = w;
            wsoft[t] = w;
        }
        __syncthreads();
        for (int i = t; i < FQ * NBQ; i += 256) {
            float lw = fminf(fmaxf(log_widths[i], -5.0f), 5.0f);
            const float rw = 1.0f / (expf(lw) + 0.1f);
            ((float2*)crw2)[i] = make_float2(rw, -centers[i] * rw);
        }
        if (t < HD) {
            float s = bias[t];
            for (int f = 0; f < FQ; ++f) s += 0.1f * ws[f] * br[f * HD + t];
            rbias[t] = s;
        }
    } else {
        const int id = (blockIdx.x - 1) * 256 + t;
        if (id < FQ * HD) {
            ((float4*)Pk)[id * 2]     = make_float4(b1[id], g1[id], be1[id], 0.0f);
            ((float4*)Pk)[id * 2 + 1] = make_float4(b2[id], g2[id], be2[id], 0.0f);
        }
    }
}

// ---------------- prep B: weight convert + swizzle into MFMA B-frag order ----
__global__ void __launch_bounds__(256) prep_swz(
    const float* __restrict__ W1, const float* __restrict__ Wr, const float* __restrict__ W2,
    unsigned short* __restrict__ W1s, unsigned short* __restrict__ Wrs,
    unsigned short* __restrict__ W2s)
{
    const int gid = blockIdx.x * 256 + threadIdx.x;
    const float* W; unsigned short* dst; int K, id;
    if (gid < 65536)       { W = W1; dst = W1s; K = 64;  id = gid; }
    else if (gid < 131072) { W = Wr; dst = Wrs; K = 64;  id = gid - 65536; }
    else                   { W = W2; dst = W2s; K = 128; id = gid - 131072; }
    const int KB = K >> 3;
    const int nn = id & 15;
    const int kb = (id >> 4) % KB;
    const int nt = ((id >> 4) / KB) & 7;
    const int f  = id / (KB * 16 * 8);
    const float* src = W + ((size_t)f * K + kb * 8) * HD + nt * 16 + nn;
    s16x8 o;
#pragma unroll
    for (int j = 0; j < 8; ++j) o[j] = (short)f2bf(src[(size_t)j * HD]);
    *(s16x8*)(dst + (size_t)f * K * HD + ((size_t)(nt * KB + kb) * 16 + nn) * 8) = o;
}

// ---------------- prep C: LDS-tiled x transpose ----------------
__global__ void __launch_bounds__(256) prep_xtr(const float* __restrict__ x,
                                                float* __restrict__ xT) {
    __shared__ float tile[64][65];
    const int t  = threadIdx.x;
    const int b0 = blockIdx.x * 64;
    {
        const int row = t & 63, cg = (t >> 6) * 16;
        const float4* src = (const float4*)(x + (size_t)(b0 + row) * FQ + cg);
#pragma unroll
        for (int i = 0; i < 4; ++i) {
            const float4 v = src[i];
            tile[row][cg + i * 4 + 0] = v.x;
            tile[row][cg + i * 4 + 1] = v.y;
            tile[row][cg + i * 4 + 2] = v.z;
            tile[row][cg + i * 4 + 3] = v.w;
        }
    }
    __syncthreads();
    {
        const int f = t >> 2, r0 = (t & 3) * 16;
        float* dst = xT + (size_t)f * BQ + b0 + r0;
#pragma unroll
        for (int i = 0; i < 16; ++i) dst[i] = tile[r0 + i][f];
    }
}

// ---------------- fused MFMA NAM body ----------------
// grid 512 = 4 fgroups x 128 row-tiles (M=128). 512 threads = 8 waves, 16 rows/wave.
// LDS exactly 64 KB -> 2 blocks/CU, 16 waves/CU.
__global__ void __launch_bounds__(NT, 4) nam_main(
    const float* __restrict__ crw2,
    const float* __restrict__ xT,
    const unsigned short* __restrict__ W1s,
    const unsigned short* __restrict__ Wrs,
    const unsigned short* __restrict__ W2s,
    const float* __restrict__ Pk,
    const float* __restrict__ wsoft,
    float* __restrict__ agg)
{
    __shared__ __align__(16) unsigned short wbuf[16384];   // 32 KB: W1+Wr, then W2
    __shared__ __align__(16) unsigned short hbuf[16384];   // 32 KB: h1g (swizzled)

    const int t    = threadIdx.x;
    const int ln   = t & 63;
    const int wv   = t >> 6;        // wave 0..7
    const int n    = ln & 15;
    const int q    = ln >> 4;
    const int wrow = wv * 16;
    const int fg   = blockIdx.x & 3;
    const int rb   = blockIdx.x >> 2;     // 0..127
    const int b0   = rb * MT;

    f32x4 acc[8];
#pragma unroll
    for (int nt = 0; nt < 8; ++nt) acc[nt] = f32x4{0.f, 0.f, 0.f, 0.f};

    for (int ff = 0; ff < FPG; ++ff) {
        const int f = fg * FPG + ((ff + rb) & (FPG - 1));   // decorrelated order
        __syncthreads();   // B0: prev iter's wbuf(W2)/hbuf(h1g) readers done

        // ---- stage W1[f]+Wr[f] (32 KB) async into wbuf ----
        {
            const unsigned short* gw1 = W1s + (size_t)f * 8192;
            const unsigned short* gwr = Wrs + (size_t)f * 8192;
#pragma unroll
            for (int i = 0; i < 4; ++i) {
                const int chunk = i * 8 + wv;   // 32 x 1KB chunks
                const unsigned short* src = (chunk < 16) ? (gw1 + chunk * 512)
                                                         : (gwr + (chunk - 16) * 512);
                load16_lds(src + ln * 8, wbuf + chunk * 512);
            }
        }

        // ---- rbf A-fragments directly in registers (no LDS round-trip) ----
        // lane needs A[m=n][k=q*8+j] (a0) and k=32+q*8+j (a1) for row wrow+n.
        s16x8 a0, a1;
        {
            float xv = xT[(size_t)f * BQ + b0 + wrow + n];
            xv = fminf(fmaxf(xv, -10.0f), 10.0f);
            const float4* c4 = ((const float4*)crw2) + f * 32;
            unsigned int p[8];
#pragma unroll
            for (int h = 0; h < 2; ++h) {
#pragma unroll
                for (int i = 0; i < 4; ++i) {
                    const float4 cc = c4[h * 16 + q * 4 + i];   // {rw,nc, rw,nc}
                    const float d0 = fmaf(xv, cc.x, cc.y);
                    const float d1 = fmaf(xv, cc.z, cc.w);
                    const float e0 = __expf(-0.5f * d0 * d0);
                    const float e1 = __expf(-0.5f * d1 * d1);
                    p[h * 4 + i] = __builtin_amdgcn_perm(__float_as_uint(e1),
                                                         __float_as_uint(e0), 0x07060302u);
                }
            }
            int4 pa = make_int4(p[0], p[1], p[2], p[3]);
            int4 pb = make_int4(p[4], p[5], p[6], p[7]);
            a0 = *(s16x8*)&pa;
            a1 = *(s16x8*)&pb;
        }
        const float wf   = wsoft[f];
        const float wf01 = 0.1f * wf;
        __syncthreads();   // B1: DMA drained, W1/Wr visible

        // ---- GEMM1 (hc) + GEMMr folded straight into acc ----
        f32x4 hc[8];
#pragma unroll
        for (int nt = 0; nt < 8; ++nt) {
            const s16x8 bA = *(const s16x8*)&wbuf[(nt * 8 + 0) * 128 + ln * 8];
            const s16x8 bB = *(const s16x8*)&wbuf[(nt * 8 + 4) * 128 + ln * 8];
            f32x4 z = f32x4{0.f, 0.f, 0.f, 0.f};
            z = __builtin_amdgcn_mfma_f32_16x16x32_bf16(a0, bA, z, 0, 0, 0);
            z = __builtin_amdgcn_mfma_f32_16x16x32_bf16(a1, bB, z, 0, 0, 0);
            hc[nt] = z;
            const s16x8 cA = *(const s16x8*)&wbuf[8192 + (nt * 8 + 0) * 128 + ln * 8];
            const s16x8 cB = *(const s16x8*)&wbuf[8192 + (nt * 8 + 4) * 128 + ln * 8];
            f32x4 y = f32x4{0.f, 0.f, 0.f, 0.f};
            y = __builtin_amdgcn_mfma_f32_16x16x32_bf16(a0, cA, y, 0, 0, 0);
            y = __builtin_amdgcn_mfma_f32_16x16x32_bf16(a1, cB, y, 0, 0, 0);
            acc[nt] = y * wf01 + acc[nt];   // residual folded now; y dies here
        }
        __syncthreads();   // B2: all waves done reading W1/Wr

        // ---- stage W2[f] (32 KB) async — overlaps LN1 VALU below ----
        {
            const unsigned short* gw2 = W2s + (size_t)f * 16384;
#pragma unroll
            for (int i = 0; i < 4; ++i) {
                const int chunk = i * 8 + wv;
                load16_lds(gw2 + chunk * 512 + ln * 8, wbuf + chunk * 512);
            }
        }

        // ---- LN1 (+b1) in registers (DPP reduce), gelu, h1g -> hbuf ----
        const size_t pkb = ((size_t)f * HD + n) * 8;
        f32x4 sm = {0.f, 0.f, 0.f, 0.f}, sq = {0.f, 0.f, 0.f, 0.f};
#pragma unroll
        for (int nt = 0; nt < 8; ++nt) {
            const float4 pA = *(const float4*)(Pk + pkb + nt * 128);
            const f32x4 v = hc[nt] + pA.x;
            hc[nt] = v; sm += v; sq += v * v;
        }
        f32x4 mu4, rs4;
#pragma unroll
        for (int i = 0; i < 4; ++i) {
            const float s  = dppsum16(sm[i]);
            const float qq = dppsum16(sq[i]);
            mu4[i] = s * (1.0f / 128.0f);
            const float var = qq * (1.0f / 128.0f) - mu4[i] * mu4[i];
            rs4[i] = rsqrtf(var + 1e-5f);
        }
#pragma unroll
        for (int nt = 0; nt < 8; ++nt) {
            const float4 pA = *(const float4*)(Pk + pkb + nt * 128);
            const f32x4 sg = rs4 * pA.y;
            const f32x4 y  = (hc[nt] - mu4) * sg + pA.z;
            const f32x4 z  = gelu4(y);
#pragma unroll
            for (int i = 0; i < 4; ++i)
                hbuf[hofs(wrow + q * 4 + i, nt * 16 + n)] = bftr(z[i]);
        }
        __syncthreads();   // B3: W2 drained + h1g visible

        // ---- GEMM2: A = h1g frags (K=128) ----
        s16x8 A2[4];
#pragma unroll
        for (int c = 0; c < 4; ++c)
            A2[c] = *(const s16x8*)&hbuf[hofs(wrow + n, c * 32 + q * 8)];
        f32x4 h2[8];
#pragma unroll
        for (int nt = 0; nt < 8; ++nt) {
            f32x4 z = f32x4{0.f, 0.f, 0.f, 0.f};
#pragma unroll
            for (int c = 0; c < 4; ++c) {
                const s16x8 bF = *(const s16x8*)&wbuf[(nt * 16 + c * 4) * 128 + ln * 8];
                z = __builtin_amdgcn_mfma_f32_16x16x32_bf16(A2[c], bF, z, 0, 0, 0);
            }
            h2[nt] = z;
        }

        // ---- LN2 (+b2), gelu, attention weight into acc ----
        sm = f32x4{0.f, 0.f, 0.f, 0.f}; sq = f32x4{0.f, 0.f, 0.f, 0.f};
#pragma unroll
        for (int nt = 0; nt < 8; ++nt) {
            const float4 pB = *(const float4*)(Pk + pkb + nt * 128 + 4);
            const f32x4 v = h2[nt] + pB.x;
            h2[nt] = v; sm += v; sq += v * v;
        }
#pragma unroll
        for (int i = 0; i < 4; ++i) {
            const float s  = dppsum16(sm[i]);
            const float qq = dppsum16(sq[i]);
            mu4[i] = s * (1.0f / 128.0f);
            const float var = qq * (1.0f / 128.0f) - mu4[i] * mu4[i];
            rs4[i] = rsqrtf(var + 1e-5f);
        }
#pragma unroll
        for (int nt = 0; nt < 8; ++nt) {
            const float4 pB = *(const float4*)(Pk + pkb + nt * 128 + 4);
            const f32x4 sg = rs4 * pB.y;
            const f32x4 y  = (h2[nt] - mu4) * sg + pB.z;
            acc[nt] = gelu4(y) * wf + acc[nt];
        }
    }

    // ---- epilogue: atomic accumulate into agg ----
    float* ap = agg + (size_t)(b0 + wrow + q * 4) * HD + n;
#pragma unroll
    for (int nt = 0; nt < 8; ++nt) {
#pragma unroll
        for (int i = 0; i < 4; ++i) {
            atomicAdd(ap + (size_t)i * HD + nt * 16, acc[nt][i]);
        }
    }
}

// ---------------- mixture-beta head: one wave per batch row ----------------
__global__ void __launch_bounds__(256) nam_head(
    const float* __restrict__ agg, const float* __restrict__ rbias,
    const float* __restrict__ Wpi, const float* __restrict__ bpi,
    const float* __restrict__ Wa,  const float* __restrict__ ba,
    const float* __restrict__ Wb,  const float* __restrict__ bb,
    float* __restrict__ out)
{
    const int gid  = blockIdx.x * blockDim.x + threadIdx.x;
    const int row  = gid >> 6;
    const int lane = threadIdx.x & 63;
    if (row >= BQ) return;

    const float2 p  = ((const float2*)(agg + (size_t)row * HD))[lane];
    const float2 rb = ((const float2*)rbias)[lane];
    const float ax = p.x + rb.x;
    const float ay = p.y + rb.y;

    const float2* wp = (const float2*)Wpi;
    const float2* wa = (const float2*)Wa;
    const float2* wb = (const float2*)Wb;
    const float2 p01 = wp[lane * 3], p23 = wp[lane * 3 + 1], p45 = wp[lane * 3 + 2];
    const float2 a01 = wa[lane * 3], a23 = wa[lane * 3 + 1], a45 = wa[lane * 3 + 2];
    const float2 b01 = wb[lane * 3], b23 = wb[lane * 3 + 1], b45 = wb[lane * 3 + 2];

    float ppi0 = ax * p01.x + ay * p23.y;
    float ppi1 = ax * p01.y + ay * p45.x;
    float ppi2 = ax * p23.x + ay * p45.y;
    float pa0  = ax * a01.x + ay * a23.y;
    float pa1  = ax * a01.y + ay * a45.x;
    float pa2  = ax * a23.x + ay * a45.y;
    float pb0  = ax * b01.x + ay * b23.y;
    float pb1  = ax * b01.y + ay * b45.x;
    float pb2  = ax * b23.x + ay * b45.y;

#pragma unroll
    for (int s = 32; s >= 1; s >>= 1) {
        ppi0 += __shfl_xor(ppi0, s, 64);
        ppi1 += __shfl_xor(ppi1, s, 64);
        ppi2 += __shfl_xor(ppi2, s, 64);
        pa0  += __shfl_xor(pa0,  s, 64);
        pa1  += __shfl_xor(pa1,  s, 64);
        pa2  += __shfl_xor(pa2,  s, 64);
        pb0  += __shfl_xor(pb0,  s, 64);
        pb1  += __shfl_xor(pb1,  s, 64);
        pb2  += __shfl_xor(pb2,  s, 64);
    }

    if (lane == 0) {
        const float z0 = ppi0 + bpi[0], z1 = ppi1 + bpi[1], z2 = ppi2 + bpi[2];
        const float mz = fmaxf(z0, fmaxf(z1, z2));
        const float e0 = expf(z0 - mz), e1 = expf(z1 - mz), e2 = expf(z2 - mz);
        const float es = e0 + e1 + e2;

        const float al0 = fminf(fmaxf(softplus_stable(pa0 + ba[0]) + 1.01f, 1.01f), 100.0f);
        const float al1 = fminf(fmaxf(softplus_stable(pa1 + ba[1]) + 1.01f, 1.01f), 100.0f);
        const float al2 = fminf(fmaxf(softplus_stable(pa2 + ba[2]) + 1.01f, 1.01f), 100.0f);
        const float bt0 = fminf(fmaxf(softplus_stable(pb0 + bb[0]) + 1.01f, 1.01f), 100.0f);
        const float bt1 = fminf(fmaxf(softplus_stable(pb1 + bb[1]) + 1.01f, 1.01f), 100.0f);
        const float bt2 = fminf(fmaxf(softplus_stable(pb2 + bb[2]) + 1.01f, 1.01f), 100.0f);

        const float pred = (e0 * (al0 / (al0 + bt0))
                          + e1 * (al1 / (al1 + bt1))
                          + e2 * (al2 / (al2 + bt2))) / es;
        out[row] = fminf(fmaxf(pred, 0.001f), 0.999f);
    }
}

extern "C" void kernel_launch(void* const* d_in, const int* in_sizes, int n_in,
                              void* d_out, int out_size, void* d_ws, size_t ws_size,
                              hipStream_t stream) {
    const float* x          = (const float*)d_in[0];
    const float* centers    = (const float*)d_in[1];
    const float* log_widths = (const float*)d_in[2];
    const float* W1   = (const float*)d_in[3];
    const float* b1   = (const float*)d_in[4];
    const float* g1   = (const float*)d_in[5];
    const float* be1  = (const float*)d_in[6];
    const float* W2   = (const float*)d_in[7];
    const float* b2   = (const float*)d_in[8];
    const float* g2   = (const float*)d_in[9];
    const float* be2  = (const float*)d_in[10];
    const float* Wr   = (const float*)d_in[11];
    const float* br   = (const float*)d_in[12];
    const float* att  = (const float*)d_in[13];
    const float* bias = (const float*)d_in[14];
    const float* Wpi  = (const float*)d_in[15];
    const float* bpi  = (const float*)d_in[16];
    const float* Wa   = (const float*)d_in[17];
    const float* ba   = (const float*)d_in[18];
    const float* Wb   = (const float*)d_in[19];
    const float* bb   = (const float*)d_in[20];

    // ---- workspace layout (byte offsets, 16B-aligned) ----
    char* ws = (char*)d_ws;
    float*          wsoft = (float*)(ws + 0);          //   256 B
    float*          rbias = (float*)(ws + 1024);       //   512 B
    float*          crw2  = (float*)(ws + 8192);       //  32 KB (float2[4096])
    float*          Pk    = (float*)(ws + 65536);      // 256 KB
    float*          xT    = (float*)(ws + 327680);     //   4 MB
    unsigned short* W1s   = (unsigned short*)(ws + 4521984);   // 1 MB
    unsigned short* Wrs   = (unsigned short*)(ws + 5570560);   // 1 MB
    unsigned short* W2s   = (unsigned short*)(ws + 6619136);   // 2 MB
    float*          agg   = (float*)(ws + 8716288);    //   8 MB

    prep_misc<<<33, 256, 0, stream>>>(att, log_widths, centers, br, bias,
                                      b1, g1, be1, b2, g2, be2,
                                      wsoft, crw2, rbias, Pk);
    prep_swz<<<1024, 256, 0, stream>>>(W1, Wr, W2, W1s, Wrs, W2s);
    prep_xtr<<<256, 256, 0, stream>>>(x, xT);
    hipMemsetAsync(agg, 0, (size_t)BQ * HD * sizeof(float), stream);

    nam_main<<<(BQ / MT) * FG, NT, 0, stream>>>(crw2, xT, W1s, Wrs, W2s, Pk,
                                                wsoft, agg);

    nam_head<<<BQ / 4, 256, 0, stream>>>(agg, rbias, Wpi, bpi, Wa, ba, Wb, bb,
                                         (float*)d_out);
}